// Round 5
// baseline (658.219 us; speedup 1.0000x reference)
//
#include <hip/hip_runtime.h>

#define NLAYER 12
#define NB 16
#define NH 12
#define NN 197
#define MAT (NN * NN)   // 38809
#define KSEL 98         // int(197 * 0.5)

// Initialize output to "not selected" = [1, 0] for every (b, n).
__global__ void init_out_kernel(float* __restrict__ out)
{
    int i = blockIdx.x * blockDim.x + threadIdx.x;  // [0, NB*NN)
    if (i < NB * NN) {
        out[2 * i + 0] = 1.f;
        out[2 * i + 1] = 0.f;
    }
}

// One block per (tensor, b, h): compute v = e0^T * A11 * A10 * ... * A0,
// select top-KSEL of v[1..196], and write [0,1] at selected (b, j).
// Multiple blocks may write the same location with identical values (benign).
__global__ __launch_bounds__(1024) void chain_topk_kernel(
    const float* __restrict__ RGB, const float* __restrict__ TIR,
    float* __restrict__ out)
{
    __shared__ float vbuf[2][NN];
    __shared__ float part[3][256];

    int bid = blockIdx.x;                 // [0, 2*NB*NH)
    int tensor = bid / (NB * NH);
    int rem = bid - tensor * (NB * NH);
    int b = rem / NH;
    int h = rem - b * NH;

    const float* A = tensor ? TIR : RGB;
    // layer l matrix base: ((l*NB + b)*NH + h) * MAT
    const size_t bh_off = (size_t)(b * NH + h) * MAT;
    const size_t l_stride = (size_t)NB * NH * MAT;

    int tid = threadIdx.x;
    int j = tid & 255;        // output column this thread owns
    int q = tid >> 8;         // k-range quarter (0..3)

    // k-split bounds: {0, 50, 100, 149, 197}
    const int kbeg[5] = {0, 50, 100, 149, 197};

    // init: v = row 0 of layer 11
    if (tid < NN) vbuf[0][tid] = A[bh_off + 11 * l_stride + tid];
    __syncthreads();

    int cur = 0;
    for (int l = 10; l >= 0; --l) {
        const float* M = A + bh_off + (size_t)l * l_stride;
        float acc = 0.f;
        if (j < NN) {
            const float* col = M + j;
            const float* v = vbuf[cur];
            const int k0 = kbeg[q];
            const int k1 = kbeg[q + 1];
            #pragma unroll 5
            for (int k = k0; k < k1; ++k)
                acc = fmaf(v[k], col[(size_t)k * NN], acc);
        }
        if (q && j < NN) part[q - 1][j] = acc;
        __syncthreads();
        if (!q && j < NN)
            vbuf[cur ^ 1][j] = acc + part[0][j] + part[1][j] + part[2][j];
        __syncthreads();
        cur ^= 1;
    }

    // top-KSEL of scores = vbuf[cur][1..196] via rank counting.
    // Strict '>' reproduces top_k's set for distinct values; a borderline
    // fp-ordering flip only changes the output if NONE of the other 23
    // (tensor,h) selections pick that element (P ~ 2^-23).
    const float* vf = vbuf[cur];
    if (tid < NN - 1) {
        float my = vf[1 + tid];
        int rank = 0;
        for (int k = 0; k < NN - 1; ++k)
            rank += (vf[1 + k] > my) ? 1 : 0;
        if (rank < KSEL) {
            // reference writes mask at index tid (NOT tid+1)
            out[2 * (b * NN + tid) + 0] = 0.f;
            out[2 * (b * NN + tid) + 1] = 1.f;
        }
    }
}

extern "C" void kernel_launch(void* const* d_in, const int* in_sizes, int n_in,
                              void* d_out, int out_size, void* d_ws, size_t ws_size,
                              hipStream_t stream) {
    const float* RGB = (const float*)d_in[0];
    const float* TIR = (const float*)d_in[1];
    float* out = (float*)d_out;

    int total = NB * NN;
    init_out_kernel<<<(total + 255) / 256, 256, 0, stream>>>(out);

    chain_topk_kernel<<<2 * NB * NH, 1024, 0, stream>>>(RGB, TIR, out);
}